// Round 2
// baseline (1248.014 us; speedup 1.0000x reference)
//
#include <hip/hip_runtime.h>

#define NN 100000
#define NE 1600000
#define HD 128
#define EPSI 1e-5f

using u32 = unsigned int;
using u16 = unsigned short;

constexpr int SCAN_CHUNK  = 1024;
constexpr int SCAN_BLOCKS = (NN + SCAN_CHUNK - 1) / SCAN_CHUNK; // 98
constexpr int BN_BLOCKS   = 256;

// ---- bf16 helpers (storage bf16, arithmetic fp32) ----
__device__ inline float bflo(u32 u) { return __uint_as_float(u << 16); }
__device__ inline float bfhi(u32 u) { return __uint_as_float(u & 0xFFFF0000u); }
__device__ inline u16 f2bf(float f) {
    u32 u = __float_as_uint(f);
    u += 0x7FFFu + ((u >> 16) & 1u); // RNE
    return (u16)(u >> 16);
}
__device__ inline u32 pack2(float a, float b) {
    return (u32)f2bf(a) | ((u32)f2bf(b) << 16);
}
__device__ inline float bf2f(u16 s) { return __uint_as_float(((u32)s) << 16); }

// ---------------- CSR build ----------------

__global__ void k_count(const int* __restrict__ dst, int* __restrict__ cnt) {
    int e = blockIdx.x * 256 + threadIdx.x;
    if (e < NE) atomicAdd(&cnt[dst[e]], 1);
}

__global__ void k_scan1(const int* __restrict__ cnt, int* __restrict__ rp,
                        int* __restrict__ tot) {
    __shared__ int lds[256];
    const int t    = threadIdx.x;
    const int base = blockIdx.x * SCAN_CHUNK + t * 4;
    int v[4];
#pragma unroll
    for (int i = 0; i < 4; ++i) v[i] = (base + i < NN) ? cnt[base + i] : 0;
    const int s = v[0] + v[1] + v[2] + v[3];
    lds[t] = s;
    __syncthreads();
    int val = s;
    for (int off = 1; off < 256; off <<= 1) {
        int other = (t >= off) ? lds[t - off] : 0;
        __syncthreads();
        val += other;
        lds[t] = val;
        __syncthreads();
    }
    int e = val - s; // exclusive prefix within block
#pragma unroll
    for (int i = 0; i < 4; ++i) {
        if (base + i < NN) rp[base + i] = e;
        e += v[i];
    }
    if (t == 255) tot[blockIdx.x] = val;
}

__global__ void k_scan2(int* __restrict__ tot, int* __restrict__ rp) {
    if (threadIdx.x == 0 && blockIdx.x == 0) {
        int run = 0;
        for (int b = 0; b < SCAN_BLOCKS; ++b) { int v = tot[b]; tot[b] = run; run += v; }
        rp[NN] = run; // == NE
    }
}

// add block offsets; zero cnt so it can be reused as the fill cursor
__global__ void k_scan3(int* __restrict__ rp, const int* __restrict__ tot,
                        int* __restrict__ cnt) {
    int idx = blockIdx.x * 256 + threadIdx.x;
    if (idx < NN) {
        rp[idx] += tot[idx >> 10];
        cnt[idx] = 0;
    }
}

__global__ void k_fill(const int* __restrict__ src, const int* __restrict__ dst,
                       const int* __restrict__ rp, int* __restrict__ fill,
                       int* __restrict__ col) {
    int e = blockIdx.x * 256 + threadIdx.x;
    if (e < NE) {
        int d = dst[e];
        int p = atomicAdd(&fill[d], 1);
        col[rp[d] + p] = src[e];
    }
}

// ---------------- mean aggregation (pull, one wave per node, bf16 rows) ----------------

__global__ void k_agg(const u16* __restrict__ h, const int* __restrict__ rp,
                      const int* __restrict__ col, u16* __restrict__ mean) {
    const int wave = threadIdx.x >> 6;
    const int lane = threadIdx.x & 63;
    const int i = blockIdx.x * 4 + wave;
    if (i >= NN) return;
    const u32* hu = reinterpret_cast<const u32*>(h);
    const int r0 = rp[i], r1 = rp[i + 1];
    float ax = 0.f, ay = 0.f;
    for (int e = r0; e < r1; ++e) {
        const int s = col[e];
        const u32 v = hu[(size_t)s * 64 + lane];
        ax += bflo(v);
        ay += bfhi(v);
    }
    const float inv = 1.0f / fmaxf((float)(r1 - r0), 1.0f);
    reinterpret_cast<u32*>(mean)[(size_t)i * 64 + lane] = pack2(ax * inv, ay * inv);
}

// ---------------- GEMM: out = A1@W1 (+ A2@W2) + bias, optional relu ----------------
// A1 fp32 (A1BF=0) or bf16 (A1BF=1); A2 always bf16 (or null); out bf16.
// 64 rows/block, 256 threads, thread tile 4 rows x 8 cols; fp32 accumulate.

template <int A1BF>
__global__ __launch_bounds__(256) void k_gemm(
    const void* __restrict__ A1p, const float* __restrict__ W1,
    const u16* __restrict__ A2, const float* __restrict__ W2,
    const float* __restrict__ bias, u16* __restrict__ out, int do_relu)
{
    __shared__ float As[64][129];
    const int t    = threadIdx.x;
    const int tcol = t & 15;  // 16 col groups * 8 cols
    const int trow = t >> 4;  // 16 row groups * 4 rows
    const int row0 = blockIdx.x * 64;

    float acc[4][8];
#pragma unroll
    for (int r = 0; r < 4; ++r)
#pragma unroll
        for (int c = 0; c < 8; ++c) acc[r][c] = 0.f;

    for (int pass = 0; pass < 2; ++pass) {
        if (pass == 1 && A2 == nullptr) continue; // uniform across block
        const float* W = pass ? W2 : W1;
        __syncthreads();
        if (pass == 0 && A1BF == 0) {
            const float* A = (const float*)A1p;
#pragma unroll
            for (int i = 0; i < 8; ++i) {
                int fid = t + 256 * i;  // 0..2047
                int r   = fid >> 5;
                int c4  = fid & 31;
                float4 v = make_float4(0.f, 0.f, 0.f, 0.f);
                if (row0 + r < NN)
                    v = *reinterpret_cast<const float4*>(&A[(size_t)(row0 + r) * HD + c4 * 4]);
                As[r][c4 * 4 + 0] = v.x;
                As[r][c4 * 4 + 1] = v.y;
                As[r][c4 * 4 + 2] = v.z;
                As[r][c4 * 4 + 3] = v.w;
            }
        } else {
            const u16* A = pass ? A2 : (const u16*)A1p;
#pragma unroll
            for (int i = 0; i < 4; ++i) {
                int fid = t + 256 * i;  // 0..1023
                int r   = fid >> 4;
                int q   = fid & 15;     // which uint4 (8 bf16) in the row
                uint4 v = make_uint4(0u, 0u, 0u, 0u);
                if (row0 + r < NN)
                    v = *reinterpret_cast<const uint4*>(&A[(size_t)(row0 + r) * HD + q * 8]);
                const int c = q * 8;
                As[r][c + 0] = bflo(v.x); As[r][c + 1] = bfhi(v.x);
                As[r][c + 2] = bflo(v.y); As[r][c + 3] = bfhi(v.y);
                As[r][c + 4] = bflo(v.z); As[r][c + 5] = bfhi(v.z);
                As[r][c + 6] = bflo(v.w); As[r][c + 7] = bfhi(v.w);
            }
        }
        __syncthreads();
#pragma unroll 4
        for (int k = 0; k < HD; ++k) {
            const float4 w0 = *reinterpret_cast<const float4*>(&W[k * HD + tcol * 8]);
            const float4 w1 = *reinterpret_cast<const float4*>(&W[k * HD + tcol * 8 + 4]);
            float a0 = As[trow * 4 + 0][k];
            float a1 = As[trow * 4 + 1][k];
            float a2 = As[trow * 4 + 2][k];
            float a3 = As[trow * 4 + 3][k];
            acc[0][0] += a0 * w0.x; acc[0][1] += a0 * w0.y; acc[0][2] += a0 * w0.z; acc[0][3] += a0 * w0.w;
            acc[0][4] += a0 * w1.x; acc[0][5] += a0 * w1.y; acc[0][6] += a0 * w1.z; acc[0][7] += a0 * w1.w;
            acc[1][0] += a1 * w0.x; acc[1][1] += a1 * w0.y; acc[1][2] += a1 * w0.z; acc[1][3] += a1 * w0.w;
            acc[1][4] += a1 * w1.x; acc[1][5] += a1 * w1.y; acc[1][6] += a1 * w1.z; acc[1][7] += a1 * w1.w;
            acc[2][0] += a2 * w0.x; acc[2][1] += a2 * w0.y; acc[2][2] += a2 * w0.z; acc[2][3] += a2 * w0.w;
            acc[2][4] += a2 * w1.x; acc[2][5] += a2 * w1.y; acc[2][6] += a2 * w1.z; acc[2][7] += a2 * w1.w;
            acc[3][0] += a3 * w0.x; acc[3][1] += a3 * w0.y; acc[3][2] += a3 * w0.z; acc[3][3] += a3 * w0.w;
            acc[3][4] += a3 * w1.x; acc[3][5] += a3 * w1.y; acc[3][6] += a3 * w1.z; acc[3][7] += a3 * w1.w;
        }
    }

    const float4 b0 = *reinterpret_cast<const float4*>(&bias[tcol * 8]);
    const float4 b1 = *reinterpret_cast<const float4*>(&bias[tcol * 8 + 4]);
#pragma unroll
    for (int rr = 0; rr < 4; ++rr) {
        int r = row0 + trow * 4 + rr;
        if (r < NN) {
            float o[8] = {acc[rr][0] + b0.x, acc[rr][1] + b0.y, acc[rr][2] + b0.z, acc[rr][3] + b0.w,
                          acc[rr][4] + b1.x, acc[rr][5] + b1.y, acc[rr][6] + b1.z, acc[rr][7] + b1.w};
            if (do_relu) {
#pragma unroll
                for (int c = 0; c < 8; ++c) o[c] = fmaxf(o[c], 0.f);
            }
            uint4 ov = make_uint4(pack2(o[0], o[1]), pack2(o[2], o[3]),
                                  pack2(o[4], o[5]), pack2(o[6], o[7]));
            *reinterpret_cast<uint4*>(&out[(size_t)r * HD + tcol * 8]) = ov;
        }
    }
}

// ---------------- BatchNorm stats (2-stage deterministic) ----------------

__global__ __launch_bounds__(256) void k_bnstat(const u16* __restrict__ out,
                                                float* __restrict__ part) {
    const int t   = threadIdx.x;
    const int j   = t & 127;
    const int sub = t >> 7;
    float s = 0.f, q = 0.f;
    for (int r = blockIdx.x * 2 + sub; r < NN; r += 2 * BN_BLOCKS) {
        float v = bf2f(out[(size_t)r * HD + j]);
        s += v;
        q += v * v;
    }
    __shared__ float ls[256], lq[256];
    ls[t] = s; lq[t] = q;
    __syncthreads();
    if (sub == 0) {
        s += ls[t + 128];
        q += lq[t + 128];
        part[blockIdx.x * 256 + j]       = s;
        part[blockIdx.x * 256 + 128 + j] = q;
    }
}

__global__ void k_bnfin(const float* __restrict__ part, const float* __restrict__ g,
                        const float* __restrict__ bt, float* __restrict__ ss) {
    const int j = threadIdx.x; // 128 threads
    float s = 0.f, q = 0.f;
    for (int b = 0; b < BN_BLOCKS; ++b) {
        s += part[b * 256 + j];
        q += part[b * 256 + 128 + j];
    }
    const float mean = s / (float)NN;
    const float var  = q / (float)NN - mean * mean;
    const float sc   = g[j] * rsqrtf(var + EPSI);
    ss[j]       = sc;
    ss[128 + j] = bt[j] - mean * sc;
}

// h = relu(out*scale + shift) + h   (bf16 in/out, 4 elems/thread)
__global__ void k_apply(const u16* __restrict__ outb, const float* __restrict__ ss,
                        u16* __restrict__ hb) {
    const size_t idx4 = (size_t)blockIdx.x * 256 + threadIdx.x;
    const size_t base = idx4 * 4;
    if (base >= (size_t)NN * HD) return;
    const int j = (int)(base & 127);
    uint2 o  = reinterpret_cast<const uint2*>(outb)[idx4];
    uint2 hv = reinterpret_cast<const uint2*>(hb)[idx4];
    float r0 = fmaxf(bflo(o.x) * ss[j + 0] + ss[128 + j + 0], 0.f) + bflo(hv.x);
    float r1 = fmaxf(bfhi(o.x) * ss[j + 1] + ss[128 + j + 1], 0.f) + bfhi(hv.x);
    float r2 = fmaxf(bflo(o.y) * ss[j + 2] + ss[128 + j + 2], 0.f) + bflo(hv.y);
    float r3 = fmaxf(bfhi(o.y) * ss[j + 3] + ss[128 + j + 3], 0.f) + bfhi(hv.y);
    reinterpret_cast<uint2*>(hb)[idx4] = make_uint2(pack2(r0, r1), pack2(r2, r3));
}

// ---------------- classifier: one wave per row ----------------

__global__ void k_cls(const u16* __restrict__ h, const float* __restrict__ w,
                      const float* __restrict__ b, float* __restrict__ out) {
    const int lane = threadIdx.x & 63;
    const int i = (int)((blockIdx.x * 256 + threadIdx.x) >> 6);
    if (i >= NN) return;
    const u32 v = reinterpret_cast<const u32*>(h)[(size_t)i * 64 + lane];
    const float h0 = bflo(v), h1 = bfhi(v);
    const float4 wv = *reinterpret_cast<const float4*>(&w[lane * 4]); // rows 2l,2l+1 of [128,2]
    float a0 = h0 * wv.x + h1 * wv.z;
    float a1 = h0 * wv.y + h1 * wv.w;
#pragma unroll
    for (int off = 32; off > 0; off >>= 1) {
        a0 += __shfl_xor(a0, off);
        a1 += __shfl_xor(a1, off);
    }
    if (lane == 0) {
        out[(size_t)i * 2 + 0] = a0 + b[0];
        out[(size_t)i * 2 + 1] = a1 + b[1];
    }
}

// ---------------- launch ----------------

extern "C" void kernel_launch(void* const* d_in, const int* in_sizes, int n_in,
                              void* d_out, int out_size, void* d_ws, size_t ws_size,
                              hipStream_t stream) {
    const float* x     = (const float*)d_in[0];
    const int*   ei    = (const int*)d_in[1];
    const float* in_w  = (const float*)d_in[2];
    const float* in_b  = (const float*)d_in[3];
    const float* cls_w = (const float*)d_in[4];
    const float* cls_b = (const float*)d_in[5];
    const float* blk_w[3][5]; // lw, lb, rw, g, bt
    for (int bidx = 0; bidx < 3; ++bidx)
        for (int k = 0; k < 5; ++k)
            blk_w[bidx][k] = (const float*)d_in[6 + bidx * 5 + k];

    const int* src = ei;
    const int* dst = ei + NE;

    // workspace layout (~58.5 MB total; big buffers are bf16)
    size_t off = 0;
    auto alloc = [&](size_t bytes) {
        void* p = (char*)d_ws + off;
        off += (bytes + 255) & ~(size_t)255;
        return p;
    };
    u16*   h      = (u16*)alloc((size_t)NN * HD * 2);   // 25.6 MB
    u16*   tmp    = (u16*)alloc((size_t)NN * HD * 2);   // 25.6 MB (mean, then pre-BN out)
    int*   rp     = (int*)alloc((size_t)(NN + 1) * 4);
    int*   cnt    = (int*)alloc((size_t)NN * 4);        // counts, then fill cursor
    int*   col    = (int*)alloc((size_t)NE * 4);        // 6.4 MB
    int*   stot   = (int*)alloc((size_t)SCAN_BLOCKS * 4);
    float* bnpart = (float*)alloc((size_t)BN_BLOCKS * 256 * 4);
    float* bnss   = (float*)alloc((size_t)256 * 4);
    (void)ws_size; (void)n_in; (void)in_sizes; (void)out_size;

    hipMemsetAsync(cnt, 0, (size_t)NN * 4, stream);

    // CSR build (cnt zeroed again inside k_scan3, reused as fill cursor by k_fill)
    k_count<<<(NE + 255) / 256, 256, 0, stream>>>(dst, cnt);
    k_scan1<<<SCAN_BLOCKS, 256, 0, stream>>>(cnt, rp, stot);
    k_scan2<<<1, 1, 0, stream>>>(stot, rp);
    k_scan3<<<(NN + 255) / 256, 256, 0, stream>>>(rp, stot, cnt);
    k_fill<<<(NE + 255) / 256, 256, 0, stream>>>(src, dst, rp, cnt, col);

    const int gemm_grid = (NN + 63) / 64;

    // input layer: h = relu(x @ in_w + in_b)   (A1 fp32)
    k_gemm<0><<<gemm_grid, 256, 0, stream>>>(x, in_w, nullptr, nullptr, in_b, h, 1);

    for (int bidx = 0; bidx < 3; ++bidx) {
        const float* lw = blk_w[bidx][0];
        const float* lb = blk_w[bidx][1];
        const float* rw = blk_w[bidx][2];
        const float* g  = blk_w[bidx][3];
        const float* bt = blk_w[bidx][4];
        k_agg<<<(NN + 3) / 4, 256, 0, stream>>>(h, rp, col, tmp);
        k_gemm<1><<<gemm_grid, 256, 0, stream>>>(tmp, lw, h, rw, lb, tmp, 0);
        k_bnstat<<<BN_BLOCKS, 256, 0, stream>>>(tmp, bnpart);
        k_bnfin<<<1, 128, 0, stream>>>(bnpart, g, bt, bnss);
        k_apply<<<(NN * HD / 4 + 255) / 256, 256, 0, stream>>>(tmp, bnss, h);
    }

    k_cls<<<(NN + 3) / 4, 256, 0, stream>>>(h, cls_w, cls_b, (float*)d_out);
}

// Round 3
// 865.649 us; speedup vs baseline: 1.4417x; 1.4417x over previous
//
#include <hip/hip_runtime.h>

#define NN 100000
#define NE 1600000
#define HD 128
#define EPSI 1e-5f

using u32 = unsigned int;
using u16 = unsigned short;

typedef short bf16x8 __attribute__((ext_vector_type(8)));
typedef float f32x4  __attribute__((ext_vector_type(4)));

constexpr int SCAN_CHUNK  = 1024;
constexpr int SCAN_BLOCKS = (NN + SCAN_CHUNK - 1) / SCAN_CHUNK; // 98
constexpr int BN_BLOCKS   = 256;

// ---- bf16 helpers (storage bf16, arithmetic fp32) ----
__device__ inline float bflo(u32 u) { return __uint_as_float(u << 16); }
__device__ inline float bfhi(u32 u) { return __uint_as_float(u & 0xFFFF0000u); }
__device__ inline u16 f2bf(float f) {
    u32 u = __float_as_uint(f);
    u += 0x7FFFu + ((u >> 16) & 1u); // RNE
    return (u16)(u >> 16);
}
__device__ inline u32 pack2(float a, float b) {
    return (u32)f2bf(a) | ((u32)f2bf(b) << 16);
}
__device__ inline float bf2f(u16 s) { return __uint_as_float(((u32)s) << 16); }

// ---------------- CSR build ----------------

__global__ void k_count(const int* __restrict__ dst, int* __restrict__ cnt) {
    int e = blockIdx.x * 256 + threadIdx.x;
    if (e < NE) atomicAdd(&cnt[dst[e]], 1);
}

__global__ void k_scan1(const int* __restrict__ cnt, int* __restrict__ rp,
                        int* __restrict__ tot) {
    __shared__ int lds[256];
    const int t    = threadIdx.x;
    const int base = blockIdx.x * SCAN_CHUNK + t * 4;
    int v[4];
#pragma unroll
    for (int i = 0; i < 4; ++i) v[i] = (base + i < NN) ? cnt[base + i] : 0;
    const int s = v[0] + v[1] + v[2] + v[3];
    lds[t] = s;
    __syncthreads();
    int val = s;
    for (int off = 1; off < 256; off <<= 1) {
        int other = (t >= off) ? lds[t - off] : 0;
        __syncthreads();
        val += other;
        lds[t] = val;
        __syncthreads();
    }
    int e = val - s; // exclusive prefix within block
#pragma unroll
    for (int i = 0; i < 4; ++i) {
        if (base + i < NN) rp[base + i] = e;
        e += v[i];
    }
    if (t == 255) tot[blockIdx.x] = val;
}

__global__ void k_scan2(int* __restrict__ tot, int* __restrict__ rp) {
    if (threadIdx.x == 0 && blockIdx.x == 0) {
        int run = 0;
        for (int b = 0; b < SCAN_BLOCKS; ++b) { int v = tot[b]; tot[b] = run; run += v; }
        rp[NN] = run; // == NE
    }
}

// add block offsets; zero cnt so it can be reused as the fill cursor
__global__ void k_scan3(int* __restrict__ rp, const int* __restrict__ tot,
                        int* __restrict__ cnt) {
    int idx = blockIdx.x * 256 + threadIdx.x;
    if (idx < NN) {
        rp[idx] += tot[idx >> 10];
        cnt[idx] = 0;
    }
}

__global__ void k_fill(const int* __restrict__ src, const int* __restrict__ dst,
                       const int* __restrict__ rp, int* __restrict__ fill,
                       int* __restrict__ col) {
    int e = blockIdx.x * 256 + threadIdx.x;
    if (e < NE) {
        int d = dst[e];
        int p = atomicAdd(&fill[d], 1);
        col[rp[d] + p] = src[e];
    }
}

// ---------------- weight prep: WT[n][k] = bf16(W[k][n]), 7 matrices ----------------

struct WTArgs { const float* w[7]; u16* o[7]; };

__global__ void k_wt(WTArgs a) {
    const int m = blockIdx.y;   // which matrix
    const int n = blockIdx.x;   // output row = W column
    const int k = threadIdx.x;  // 128
    a.o[m][n * HD + k] = f2bf(a.w[m][k * HD + n]);
}

// ---------------- mean aggregation (pull, one wave per node, 4x edge unroll) ----------------

__global__ void k_agg(const u16* __restrict__ h, const int* __restrict__ rp,
                      const int* __restrict__ col, u16* __restrict__ mean) {
    const int wave = threadIdx.x >> 6;
    const int lane = threadIdx.x & 63;
    const int i = blockIdx.x * 4 + wave;
    if (i >= NN) return;
    const u32* hu = reinterpret_cast<const u32*>(h);
    const int r0 = rp[i], r1 = rp[i + 1];
    float ax0 = 0.f, ay0 = 0.f, ax1 = 0.f, ay1 = 0.f;
    float ax2 = 0.f, ay2 = 0.f, ax3 = 0.f, ay3 = 0.f;
    int e = r0;
    for (; e + 4 <= r1; e += 4) {
        const int s0 = col[e], s1 = col[e + 1], s2 = col[e + 2], s3 = col[e + 3];
        const u32 v0 = hu[((size_t)s0 << 6) + lane];
        const u32 v1 = hu[((size_t)s1 << 6) + lane];
        const u32 v2 = hu[((size_t)s2 << 6) + lane];
        const u32 v3 = hu[((size_t)s3 << 6) + lane];
        ax0 += bflo(v0); ay0 += bfhi(v0);
        ax1 += bflo(v1); ay1 += bfhi(v1);
        ax2 += bflo(v2); ay2 += bfhi(v2);
        ax3 += bflo(v3); ay3 += bfhi(v3);
    }
    for (; e < r1; ++e) {
        const u32 v = hu[((size_t)col[e] << 6) + lane];
        ax0 += bflo(v); ay0 += bfhi(v);
    }
    const float ax = (ax0 + ax1) + (ax2 + ax3);
    const float ay = (ay0 + ay1) + (ay2 + ay3);
    const float inv = 1.0f / fmaxf((float)(r1 - r0), 1.0f);
    reinterpret_cast<u32*>(mean)[((size_t)i << 6) + lane] = pack2(ax * inv, ay * inv);
}

// ---------------- MFMA GEMM: out = A1@W1 (+ A2@W2) + bias, optional relu ----------------
// 256 threads = 4 waves; block tile 64x128; wave tile 16x128.
// A1 fp32 (A1F32=1) or bf16; A2 bf16 or null. W*T are transposed bf16 [N][K].
// MFMA 16x16x32 bf16: A row=lane&15,k=(lane>>4)*8+j ; B col=lane&15 same k ;
// D col=lane&15, row=(lane>>4)*4+reg  (verified layout).

template <int A1F32>
__global__ __launch_bounds__(256) void k_mgemm(
    const void* __restrict__ A1p, const u16* __restrict__ W1T,
    const u16* __restrict__ A2, const u16* __restrict__ W2T,
    const float* __restrict__ bias, u16* __restrict__ out, int do_relu)
{
    const int t    = threadIdx.x;
    const int wv   = t >> 6;
    const int lane = t & 63;
    const int lid  = lane & 15;   // A-row / B-col / D-col within tile
    const int kseg = lane >> 4;   // 0..3
    const int row0 = blockIdx.x * 64 + wv * 16;
    const int r    = row0 + lid;
    const bool rok = r < NN;

    f32x4 acc[8];
#pragma unroll
    for (int c = 0; c < 8; ++c) acc[c] = (f32x4){0.f, 0.f, 0.f, 0.f};

    for (int pass = 0; pass < 2; ++pass) {
        if (pass == 1 && A2 == nullptr) break;
        const u16* WT = pass ? W2T : W1T;
#pragma unroll
        for (int kk = 0; kk < 4; ++kk) {
            const int kof = kk * 32 + kseg * 8;
            bf16x8 af;
            if (A1F32 && pass == 0) {
                const float* A = (const float*)A1p;
                if (rok) {
                    const float4 f0 = *reinterpret_cast<const float4*>(&A[(size_t)r * HD + kof]);
                    const float4 f1 = *reinterpret_cast<const float4*>(&A[(size_t)r * HD + kof + 4]);
                    af[0] = (short)f2bf(f0.x); af[1] = (short)f2bf(f0.y);
                    af[2] = (short)f2bf(f0.z); af[3] = (short)f2bf(f0.w);
                    af[4] = (short)f2bf(f1.x); af[5] = (short)f2bf(f1.y);
                    af[6] = (short)f2bf(f1.z); af[7] = (short)f2bf(f1.w);
                } else {
                    af = (bf16x8)0;
                }
            } else {
                const u16* A = pass ? A2 : (const u16*)A1p;
                af = rok ? *reinterpret_cast<const bf16x8*>(&A[(size_t)r * HD + kof])
                         : (bf16x8)0;
            }
#pragma unroll
            for (int c = 0; c < 8; ++c) {
                const bf16x8 bf =
                    *reinterpret_cast<const bf16x8*>(&WT[(size_t)(c * 16 + lid) * HD + kof]);
                acc[c] = __builtin_amdgcn_mfma_f32_16x16x32_bf16(af, bf, acc[c], 0, 0, 0);
            }
        }
    }

#pragma unroll
    for (int c = 0; c < 8; ++c) {
        const int colc = c * 16 + lid;
        const float bv = bias[colc];
#pragma unroll
        for (int j = 0; j < 4; ++j) {
            const int rr = row0 + kseg * 4 + j;
            if (rr < NN) {
                float o = acc[c][j] + bv;
                if (do_relu) o = fmaxf(o, 0.f);
                out[(size_t)rr * HD + colc] = f2bf(o);
            }
        }
    }
}

// ---------------- BatchNorm stats (2-stage deterministic) ----------------

__global__ __launch_bounds__(256) void k_bnstat(const u16* __restrict__ out,
                                                float* __restrict__ part) {
    const int t   = threadIdx.x;
    const int j   = t & 127;
    const int sub = t >> 7;
    float s = 0.f, q = 0.f;
    for (int r = blockIdx.x * 2 + sub; r < NN; r += 2 * BN_BLOCKS) {
        float v = bf2f(out[(size_t)r * HD + j]);
        s += v;
        q += v * v;
    }
    __shared__ float ls[256], lq[256];
    ls[t] = s; lq[t] = q;
    __syncthreads();
    if (sub == 0) {
        s += ls[t + 128];
        q += lq[t + 128];
        part[blockIdx.x * 256 + j]       = s;
        part[blockIdx.x * 256 + 128 + j] = q;
    }
}

__global__ void k_bnfin(const float* __restrict__ part, const float* __restrict__ g,
                        const float* __restrict__ bt, float* __restrict__ ss) {
    const int j = threadIdx.x; // 128 threads
    float s = 0.f, q = 0.f;
    for (int b = 0; b < BN_BLOCKS; ++b) {
        s += part[b * 256 + j];
        q += part[b * 256 + 128 + j];
    }
    const float mean = s / (float)NN;
    const float var  = q / (float)NN - mean * mean;
    const float sc   = g[j] * rsqrtf(var + EPSI);
    ss[j]       = sc;
    ss[128 + j] = bt[j] - mean * sc;
}

// h = relu(out*scale + shift) + h   (bf16 in/out, 4 elems/thread)
__global__ void k_apply(const u16* __restrict__ outb, const float* __restrict__ ss,
                        u16* __restrict__ hb) {
    const size_t idx4 = (size_t)blockIdx.x * 256 + threadIdx.x;
    const size_t base = idx4 * 4;
    if (base >= (size_t)NN * HD) return;
    const int j = (int)(base & 127);
    uint2 o  = reinterpret_cast<const uint2*>(outb)[idx4];
    uint2 hv = reinterpret_cast<const uint2*>(hb)[idx4];
    float r0 = fmaxf(bflo(o.x) * ss[j + 0] + ss[128 + j + 0], 0.f) + bflo(hv.x);
    float r1 = fmaxf(bfhi(o.x) * ss[j + 1] + ss[128 + j + 1], 0.f) + bfhi(hv.x);
    float r2 = fmaxf(bflo(o.y) * ss[j + 2] + ss[128 + j + 2], 0.f) + bflo(hv.y);
    float r3 = fmaxf(bfhi(o.y) * ss[j + 3] + ss[128 + j + 3], 0.f) + bfhi(hv.y);
    reinterpret_cast<uint2*>(hb)[idx4] = make_uint2(pack2(r0, r1), pack2(r2, r3));
}

// ---------------- classifier: one wave per row ----------------

__global__ void k_cls(const u16* __restrict__ h, const float* __restrict__ w,
                      const float* __restrict__ b, float* __restrict__ out) {
    const int lane = threadIdx.x & 63;
    const int i = (int)((blockIdx.x * 256 + threadIdx.x) >> 6);
    if (i >= NN) return;
    const u32 v = reinterpret_cast<const u32*>(h)[(size_t)i * 64 + lane];
    const float h0 = bflo(v), h1 = bfhi(v);
    const float4 wv = *reinterpret_cast<const float4*>(&w[lane * 4]); // rows 2l,2l+1 of [128,2]
    float a0 = h0 * wv.x + h1 * wv.z;
    float a1 = h0 * wv.y + h1 * wv.w;
#pragma unroll
    for (int off = 32; off > 0; off >>= 1) {
        a0 += __shfl_xor(a0, off);
        a1 += __shfl_xor(a1, off);
    }
    if (lane == 0) {
        out[(size_t)i * 2 + 0] = a0 + b[0];
        out[(size_t)i * 2 + 1] = a1 + b[1];
    }
}

// ---------------- launch ----------------

extern "C" void kernel_launch(void* const* d_in, const int* in_sizes, int n_in,
                              void* d_out, int out_size, void* d_ws, size_t ws_size,
                              hipStream_t stream) {
    const float* x     = (const float*)d_in[0];
    const int*   ei    = (const int*)d_in[1];
    const float* in_w  = (const float*)d_in[2];
    const float* in_b  = (const float*)d_in[3];
    const float* cls_w = (const float*)d_in[4];
    const float* cls_b = (const float*)d_in[5];
    const float* blk_w[3][5]; // lw, lb, rw, g, bt
    for (int bidx = 0; bidx < 3; ++bidx)
        for (int k = 0; k < 5; ++k)
            blk_w[bidx][k] = (const float*)d_in[6 + bidx * 5 + k];

    const int* src = ei;
    const int* dst = ei + NE;

    // workspace layout (~59 MB; big buffers bf16)
    size_t off = 0;
    auto alloc = [&](size_t bytes) {
        void* p = (char*)d_ws + off;
        off += (bytes + 255) & ~(size_t)255;
        return p;
    };
    u16*   h      = (u16*)alloc((size_t)NN * HD * 2);   // 25.6 MB
    u16*   tmp    = (u16*)alloc((size_t)NN * HD * 2);   // 25.6 MB (mean, then pre-BN out)
    int*   rp     = (int*)alloc((size_t)(NN + 1) * 4);
    int*   cnt    = (int*)alloc((size_t)NN * 4);        // counts, then fill cursor
    int*   col    = (int*)alloc((size_t)NE * 4);        // 6.4 MB
    int*   stot   = (int*)alloc((size_t)SCAN_BLOCKS * 4);
    float* bnpart = (float*)alloc((size_t)BN_BLOCKS * 256 * 4);
    float* bnss   = (float*)alloc((size_t)256 * 4);
    u16*   wtb    = (u16*)alloc((size_t)7 * HD * HD * 2); // 224 KB transposed bf16 weights
    (void)ws_size; (void)n_in; (void)in_sizes; (void)out_size;

    hipMemsetAsync(cnt, 0, (size_t)NN * 4, stream);

    // transposed bf16 weights: [0]=in_w, then per block lw, rw
    WTArgs wa;
    wa.w[0] = in_w;
    for (int bidx = 0; bidx < 3; ++bidx) {
        wa.w[1 + bidx * 2] = blk_w[bidx][0]; // lw
        wa.w[2 + bidx * 2] = blk_w[bidx][2]; // rw
    }
    for (int m = 0; m < 7; ++m) wa.o[m] = wtb + (size_t)m * HD * HD;
    k_wt<<<dim3(HD, 7), HD, 0, stream>>>(wa);

    // CSR build (cnt zeroed again inside k_scan3, reused as fill cursor by k_fill)
    k_count<<<(NE + 255) / 256, 256, 0, stream>>>(dst, cnt);
    k_scan1<<<SCAN_BLOCKS, 256, 0, stream>>>(cnt, rp, stot);
    k_scan2<<<1, 1, 0, stream>>>(stot, rp);
    k_scan3<<<(NN + 255) / 256, 256, 0, stream>>>(rp, stot, cnt);
    k_fill<<<(NE + 255) / 256, 256, 0, stream>>>(src, dst, rp, cnt, col);

    const int gemm_grid = (NN + 63) / 64;

    // input layer: h = relu(x @ in_w + in_b)   (A1 fp32 -> bf16 frags inline)
    k_mgemm<1><<<gemm_grid, 256, 0, stream>>>(x, wtb, nullptr, nullptr, in_b, h, 1);

    for (int bidx = 0; bidx < 3; ++bidx) {
        const u16* lwT = wtb + (size_t)(1 + bidx * 2) * HD * HD;
        const u16* rwT = wtb + (size_t)(2 + bidx * 2) * HD * HD;
        const float* lb = blk_w[bidx][1];
        const float* g  = blk_w[bidx][3];
        const float* bt = blk_w[bidx][4];
        k_agg<<<(NN + 3) / 4, 256, 0, stream>>>(h, rp, col, tmp);
        k_mgemm<0><<<gemm_grid, 256, 0, stream>>>(tmp, lwT, h, rwT, lb, tmp, 0);
        k_bnstat<<<BN_BLOCKS, 256, 0, stream>>>(tmp, bnpart);
        k_bnfin<<<1, 128, 0, stream>>>(bnpart, g, bt, bnss);
        k_apply<<<(NN * HD / 4 + 255) / 256, 256, 0, stream>>>(tmp, bnss, h);
    }

    k_cls<<<(NN + 3) / 4, 256, 0, stream>>>(h, cls_w, cls_b, (float*)d_out);
}

// Round 4
// 753.775 us; speedup vs baseline: 1.6557x; 1.1484x over previous
//
#include <hip/hip_runtime.h>

#define NN 100000
#define NE 1600000
#define HD 128
#define EPSI 1e-5f

using u32 = unsigned int;
using u16 = unsigned short;

typedef short bf16x8 __attribute__((ext_vector_type(8)));
typedef float f32x4  __attribute__((ext_vector_type(4)));

constexpr int SCAN_CHUNK  = 1024;
constexpr int SCAN_BLOCKS = (NN + SCAN_CHUNK - 1) / SCAN_CHUNK; // 98

// ---- bf16 helpers (storage bf16, arithmetic fp32) ----
__device__ inline float bflo(u32 u) { return __uint_as_float(u << 16); }
__device__ inline float bfhi(u32 u) { return __uint_as_float(u & 0xFFFF0000u); }
__device__ inline u16 f2bf(float f) {
    u32 u = __float_as_uint(f);
    u += 0x7FFFu + ((u >> 16) & 1u); // RNE
    return (u16)(u >> 16);
}
__device__ inline u32 pack2(float a, float b) {
    return (u32)f2bf(a) | ((u32)f2bf(b) << 16);
}

// ---------------- CSR build ----------------

__global__ void k_count(const int* __restrict__ dst, int* __restrict__ cnt) {
    const int e0 = (blockIdx.x * 256 + threadIdx.x) * 4;
    if (e0 >= NE) return;
    const int4 d4 = *reinterpret_cast<const int4*>(&dst[e0]); // NE % 4 == 0
    atomicAdd(&cnt[d4.x], 1);
    atomicAdd(&cnt[d4.y], 1);
    atomicAdd(&cnt[d4.z], 1);
    atomicAdd(&cnt[d4.w], 1);
}

__global__ void k_scan1(const int* __restrict__ cnt, int* __restrict__ rp,
                        int* __restrict__ tot) {
    __shared__ int lds[256];
    const int t    = threadIdx.x;
    const int base = blockIdx.x * SCAN_CHUNK + t * 4;
    int v[4];
#pragma unroll
    for (int i = 0; i < 4; ++i) v[i] = (base + i < NN) ? cnt[base + i] : 0;
    const int s = v[0] + v[1] + v[2] + v[3];
    lds[t] = s;
    __syncthreads();
    int val = s;
    for (int off = 1; off < 256; off <<= 1) {
        int other = (t >= off) ? lds[t - off] : 0;
        __syncthreads();
        val += other;
        lds[t] = val;
        __syncthreads();
    }
    int e = val - s; // exclusive prefix within block
#pragma unroll
    for (int i = 0; i < 4; ++i) {
        if (base + i < NN) rp[base + i] = e;
        e += v[i];
    }
    if (t == 255) tot[blockIdx.x] = val;
}

__global__ void k_scan2(int* __restrict__ tot, int* __restrict__ rp) {
    if (threadIdx.x == 0 && blockIdx.x == 0) {
        int run = 0;
        for (int b = 0; b < SCAN_BLOCKS; ++b) { int v = tot[b]; tot[b] = run; run += v; }
        rp[NN] = run; // == NE
    }
}

// add block offsets; zero cnt so it can be reused as the fill cursor
__global__ void k_scan3(int* __restrict__ rp, const int* __restrict__ tot,
                        int* __restrict__ cnt) {
    int idx = blockIdx.x * 256 + threadIdx.x;
    if (idx < NN) {
        rp[idx] += tot[idx >> 10];
        cnt[idx] = 0;
    }
}

__global__ void k_fill(const int* __restrict__ src, const int* __restrict__ dst,
                       const int* __restrict__ rp, int* __restrict__ fill,
                       int* __restrict__ col) {
    const int e0 = (blockIdx.x * 256 + threadIdx.x) * 4;
    if (e0 >= NE) return;
    const int4 d4 = *reinterpret_cast<const int4*>(&dst[e0]);
    const int4 s4 = *reinterpret_cast<const int4*>(&src[e0]);
    const int p0 = atomicAdd(&fill[d4.x], 1);
    const int p1 = atomicAdd(&fill[d4.y], 1);
    const int p2 = atomicAdd(&fill[d4.z], 1);
    const int p3 = atomicAdd(&fill[d4.w], 1);
    col[rp[d4.x] + p0] = s4.x;
    col[rp[d4.y] + p1] = s4.y;
    col[rp[d4.z] + p2] = s4.z;
    col[rp[d4.w] + p3] = s4.w;
}

// ---------------- weight prep: WT[n][k] = bf16(W[k][n]), 7 matrices ----------------

struct WTArgs { const float* w[7]; u16* o[7]; };

__global__ void k_wt(WTArgs a) {
    const int m = blockIdx.y;   // which matrix
    const int n = blockIdx.x;   // output row = W column
    const int k = threadIdx.x;  // 128
    a.o[m][n * HD + k] = f2bf(a.w[m][k * HD + n]);
}

// ---------------- mean aggregation: 16 lanes/node, 4 nodes/wave, 4x unroll ----------------

__device__ inline void acc8(float* a, uint4 v) {
    a[0] += bflo(v.x); a[1] += bfhi(v.x);
    a[2] += bflo(v.y); a[3] += bfhi(v.y);
    a[4] += bflo(v.z); a[5] += bfhi(v.z);
    a[6] += bflo(v.w); a[7] += bfhi(v.w);
}

__global__ __launch_bounds__(256) void k_agg(const u16* __restrict__ h,
                                             const int* __restrict__ rp,
                                             const int* __restrict__ col,
                                             u16* __restrict__ mean) {
    const int t    = threadIdx.x;
    const int li   = t & 15;                     // lane within node (16B chunk)
    const int node = blockIdx.x * 16 + (t >> 4); // 16 nodes per block (NN % 16 == 0)
    const int r0 = rp[node], r1 = rp[node + 1];
    const size_t lof = (size_t)li * 8;
    float a[8];
#pragma unroll
    for (int i = 0; i < 8; ++i) a[i] = 0.f;
    int e = r0;
    for (; e + 4 <= r1; e += 4) {
        const int s0 = col[e], s1 = col[e + 1], s2 = col[e + 2], s3 = col[e + 3];
        const uint4 v0 = *reinterpret_cast<const uint4*>(&h[(size_t)s0 * HD + lof]);
        const uint4 v1 = *reinterpret_cast<const uint4*>(&h[(size_t)s1 * HD + lof]);
        const uint4 v2 = *reinterpret_cast<const uint4*>(&h[(size_t)s2 * HD + lof]);
        const uint4 v3 = *reinterpret_cast<const uint4*>(&h[(size_t)s3 * HD + lof]);
        acc8(a, v0); acc8(a, v1); acc8(a, v2); acc8(a, v3);
    }
    for (; e < r1; ++e) {
        const uint4 v = *reinterpret_cast<const uint4*>(&h[(size_t)col[e] * HD + lof]);
        acc8(a, v);
    }
    const float inv = 1.0f / fmaxf((float)(r1 - r0), 1.0f);
    uint4 o;
    o.x = pack2(a[0] * inv, a[1] * inv);
    o.y = pack2(a[2] * inv, a[3] * inv);
    o.z = pack2(a[4] * inv, a[5] * inv);
    o.w = pack2(a[6] * inv, a[7] * inv);
    *reinterpret_cast<uint4*>(&mean[(size_t)node * HD + lof]) = o;
}

// ---------------- MFMA GEMM: out = A1@W1 (+ A2@W2) + bias ----------------
// 256 threads = 4 waves; block tile 64x128; wave tile 16x128.
// STATS: accumulate column sum/sumsq of (pre-relu) outputs into stats[256] via
// wave shuffle -> LDS -> 256 global atomicAdds per block.

template <int A1F32, int RELU, int STATS>
__global__ __launch_bounds__(256) void k_mgemm(
    const void* __restrict__ A1p, const u16* __restrict__ W1T,
    const u16* __restrict__ A2, const u16* __restrict__ W2T,
    const float* __restrict__ bias, u16* __restrict__ out,
    float* __restrict__ stats)
{
    const int t    = threadIdx.x;
    const int wv   = t >> 6;
    const int lane = t & 63;
    const int lid  = lane & 15;   // A-row / B-col / D-col within tile
    const int kseg = lane >> 4;   // 0..3
    const int row0 = blockIdx.x * 64 + wv * 16;
    const int r    = row0 + lid;
    const bool rok = r < NN;

    f32x4 acc[8];
#pragma unroll
    for (int c = 0; c < 8; ++c) acc[c] = (f32x4){0.f, 0.f, 0.f, 0.f};

    for (int pass = 0; pass < 2; ++pass) {
        if (pass == 1 && A2 == nullptr) break;
        const u16* WT = pass ? W2T : W1T;
#pragma unroll
        for (int kk = 0; kk < 4; ++kk) {
            const int kof = kk * 32 + kseg * 8;
            bf16x8 af;
            if (A1F32 && pass == 0) {
                const float* A = (const float*)A1p;
                if (rok) {
                    const float4 f0 = *reinterpret_cast<const float4*>(&A[(size_t)r * HD + kof]);
                    const float4 f1 = *reinterpret_cast<const float4*>(&A[(size_t)r * HD + kof + 4]);
                    af[0] = (short)f2bf(f0.x); af[1] = (short)f2bf(f0.y);
                    af[2] = (short)f2bf(f0.z); af[3] = (short)f2bf(f0.w);
                    af[4] = (short)f2bf(f1.x); af[5] = (short)f2bf(f1.y);
                    af[6] = (short)f2bf(f1.z); af[7] = (short)f2bf(f1.w);
                } else {
                    af = (bf16x8)0;
                }
            } else {
                const u16* A = pass ? A2 : (const u16*)A1p;
                af = rok ? *reinterpret_cast<const bf16x8*>(&A[(size_t)r * HD + kof])
                         : (bf16x8)0;
            }
#pragma unroll
            for (int c = 0; c < 8; ++c) {
                const bf16x8 bf =
                    *reinterpret_cast<const bf16x8*>(&WT[(size_t)(c * 16 + lid) * HD + kof]);
                acc[c] = __builtin_amdgcn_mfma_f32_16x16x32_bf16(af, bf, acc[c], 0, 0, 0);
            }
        }
    }

    float sv[8], qv[8];
#pragma unroll
    for (int c = 0; c < 8; ++c) {
        const int colc = c * 16 + lid;
        const float bv = bias[colc];
        float s = 0.f, q = 0.f;
#pragma unroll
        for (int j = 0; j < 4; ++j) {
            const int rr = row0 + kseg * 4 + j;
            if (rr < NN) {
                float o = acc[c][j] + bv;
                if (RELU) o = fmaxf(o, 0.f);
                out[(size_t)rr * HD + colc] = f2bf(o);
                s += o;
                q += o * o;
            }
        }
        sv[c] = s; qv[c] = q;
    }

    if constexpr (STATS) {
        __shared__ float ls[4][HD], lq[4][HD];
#pragma unroll
        for (int c = 0; c < 8; ++c) {
            sv[c] += __shfl_xor(sv[c], 16);
            sv[c] += __shfl_xor(sv[c], 32);
            qv[c] += __shfl_xor(qv[c], 16);
            qv[c] += __shfl_xor(qv[c], 32);
        }
        if (lane < 16) {
#pragma unroll
            for (int c = 0; c < 8; ++c) {
                ls[wv][c * 16 + lid] = sv[c];
                lq[wv][c * 16 + lid] = qv[c];
            }
        }
        __syncthreads();
        if (t < HD) {
            const float s = (ls[0][t] + ls[1][t]) + (ls[2][t] + ls[3][t]);
            atomicAdd(&stats[t], s);
        } else {
            const int j = t - HD;
            const float q = (lq[0][j] + lq[1][j]) + (lq[2][j] + lq[3][j]);
            atomicAdd(&stats[HD + j], q);
        }
    }
}

// ---------------- fused BN-finalize + relu + residual (+ classifier) ----------------
// thread covers 4 cols of one row; 32 threads per row.

template <int CLS>
__global__ __launch_bounds__(256) void k_apply(
    const u16* __restrict__ outb, const float* __restrict__ stats,
    const float* __restrict__ g, const float* __restrict__ bt,
    u16* __restrict__ hb, const float* __restrict__ cw,
    const float* __restrict__ cb, float* __restrict__ logits)
{
    const int t = threadIdx.x;
    const size_t idx4 = (size_t)blockIdx.x * 256 + t;
    const int j = (int)(idx4 & 31) * 4; // column base
    const float4 svv = *reinterpret_cast<const float4*>(&stats[j]);
    const float4 qvv = *reinterpret_cast<const float4*>(&stats[HD + j]);
    const float4 gv  = *reinterpret_cast<const float4*>(&g[j]);
    const float4 bv  = *reinterpret_cast<const float4*>(&bt[j]);
    const float invn = 1.0f / (float)NN;
    float sc[4], sh[4];
    {
        const float sa[4] = {svv.x, svv.y, svv.z, svv.w};
        const float qa[4] = {qvv.x, qvv.y, qvv.z, qvv.w};
        const float ga[4] = {gv.x, gv.y, gv.z, gv.w};
        const float ba[4] = {bv.x, bv.y, bv.z, bv.w};
#pragma unroll
        for (int i = 0; i < 4; ++i) {
            const float mean = sa[i] * invn;
            const float var  = qa[i] * invn - mean * mean;
            sc[i] = ga[i] * rsqrtf(var + EPSI);
            sh[i] = ba[i] - mean * sc[i];
        }
    }
    const uint2 o  = reinterpret_cast<const uint2*>(outb)[idx4];
    const uint2 hv = reinterpret_cast<const uint2*>(hb)[idx4];
    const float r0 = fmaxf(bflo(o.x) * sc[0] + sh[0], 0.f) + bflo(hv.x);
    const float r1 = fmaxf(bfhi(o.x) * sc[1] + sh[1], 0.f) + bfhi(hv.x);
    const float r2 = fmaxf(bflo(o.y) * sc[2] + sh[2], 0.f) + bflo(hv.y);
    const float r3 = fmaxf(bfhi(o.y) * sc[3] + sh[3], 0.f) + bfhi(hv.y);
    reinterpret_cast<uint2*>(hb)[idx4] = make_uint2(pack2(r0, r1), pack2(r2, r3));

    if constexpr (CLS) {
        const float4 w01 = *reinterpret_cast<const float4*>(&cw[j * 2]);
        const float4 w23 = *reinterpret_cast<const float4*>(&cw[j * 2 + 4]);
        float p0 = r0 * w01.x + r1 * w01.z + r2 * w23.x + r3 * w23.z;
        float p1 = r0 * w01.y + r1 * w01.w + r2 * w23.y + r3 * w23.w;
#pragma unroll
        for (int off = 1; off <= 16; off <<= 1) {
            p0 += __shfl_xor(p0, off);
            p1 += __shfl_xor(p1, off);
        }
        if ((t & 31) == 0) {
            const size_t row = idx4 >> 5;
            logits[row * 2 + 0] = p0 + cb[0];
            logits[row * 2 + 1] = p1 + cb[1];
        }
    }
}

// ---------------- launch ----------------

extern "C" void kernel_launch(void* const* d_in, const int* in_sizes, int n_in,
                              void* d_out, int out_size, void* d_ws, size_t ws_size,
                              hipStream_t stream) {
    const float* x     = (const float*)d_in[0];
    const int*   ei    = (const int*)d_in[1];
    const float* in_w  = (const float*)d_in[2];
    const float* in_b  = (const float*)d_in[3];
    const float* cls_w = (const float*)d_in[4];
    const float* cls_b = (const float*)d_in[5];
    const float* blk_w[3][5]; // lw, lb, rw, g, bt
    for (int bidx = 0; bidx < 3; ++bidx)
        for (int k = 0; k < 5; ++k)
            blk_w[bidx][k] = (const float*)d_in[6 + bidx * 5 + k];

    const int* src = ei;
    const int* dst = ei + NE;

    // workspace layout (~59 MB; big buffers bf16)
    size_t off = 0;
    auto alloc = [&](size_t bytes) {
        void* p = (char*)d_ws + off;
        off += (bytes + 255) & ~(size_t)255;
        return p;
    };
    u16*   h     = (u16*)alloc((size_t)NN * HD * 2);   // 25.6 MB
    u16*   tmp   = (u16*)alloc((size_t)NN * HD * 2);   // 25.6 MB (mean, then pre-BN out)
    int*   rp    = (int*)alloc((size_t)(NN + 1) * 4);
    int*   cnt   = (int*)alloc((size_t)NN * 4);        // counts, then fill cursor
    float* stats = (float*)alloc((size_t)3 * 256 * 4); // adjacent to cnt: one memset
    int*   col   = (int*)alloc((size_t)NE * 4);        // 6.4 MB
    int*   stot  = (int*)alloc((size_t)SCAN_BLOCKS * 4);
    u16*   wtb   = (u16*)alloc((size_t)7 * HD * HD * 2); // 224 KB transposed bf16 weights
    (void)ws_size; (void)n_in; (void)in_sizes; (void)out_size;

    // zero cnt + the 3 stats buffers in one memset (allocated adjacently)
    const size_t cnt_pad = ((size_t)NN * 4 + 255) & ~(size_t)255;
    hipMemsetAsync(cnt, 0, cnt_pad + 3 * 256 * 4, stream);

    // transposed bf16 weights: [0]=in_w, then per block lw, rw
    WTArgs wa;
    wa.w[0] = in_w;
    for (int bidx = 0; bidx < 3; ++bidx) {
        wa.w[1 + bidx * 2] = blk_w[bidx][0]; // lw
        wa.w[2 + bidx * 2] = blk_w[bidx][2]; // rw
    }
    for (int m = 0; m < 7; ++m) wa.o[m] = wtb + (size_t)m * HD * HD;
    k_wt<<<dim3(HD, 7), HD, 0, stream>>>(wa);

    // CSR build
    const int egrid4 = (NE / 4 + 255) / 256;
    k_count<<<egrid4, 256, 0, stream>>>(dst, cnt);
    k_scan1<<<SCAN_BLOCKS, 256, 0, stream>>>(cnt, rp, stot);
    k_scan2<<<1, 1, 0, stream>>>(stot, rp);
    k_scan3<<<(NN + 255) / 256, 256, 0, stream>>>(rp, stot, cnt);
    k_fill<<<egrid4, 256, 0, stream>>>(src, dst, rp, cnt, col);

    const int gemm_grid  = (NN + 63) / 64;
    const int apply_grid = NN * 32 / 256; // 12500, exact

    // input layer: h = relu(x @ in_w + in_b)
    k_mgemm<1, 1, 0><<<gemm_grid, 256, 0, stream>>>(x, wtb, nullptr, nullptr, in_b, h, nullptr);

    for (int bidx = 0; bidx < 3; ++bidx) {
        const u16* lwT = wtb + (size_t)(1 + bidx * 2) * HD * HD;
        const u16* rwT = wtb + (size_t)(2 + bidx * 2) * HD * HD;
        const float* lb = blk_w[bidx][1];
        const float* g  = blk_w[bidx][3];
        const float* bt = blk_w[bidx][4];
        float* st = stats + bidx * 256;
        k_agg<<<NN / 16, 256, 0, stream>>>(h, rp, col, tmp);
        k_mgemm<0, 0, 1><<<gemm_grid, 256, 0, stream>>>(tmp, lwT, h, rwT, lb, tmp, st);
        if (bidx < 2)
            k_apply<0><<<apply_grid, 256, 0, stream>>>(tmp, st, g, bt, h,
                                                       nullptr, nullptr, nullptr);
        else
            k_apply<1><<<apply_grid, 256, 0, stream>>>(tmp, st, g, bt, h,
                                                       cls_w, cls_b, (float*)d_out);
    }
}

// Round 5
// 695.773 us; speedup vs baseline: 1.7937x; 1.0834x over previous
//
#include <hip/hip_runtime.h>

#define NN 100000
#define NE 1600000
#define HD 128
#define EPSI 1e-5f

using u32 = unsigned int;
using u16 = unsigned short;

typedef short bf16x8 __attribute__((ext_vector_type(8)));
typedef float f32x4  __attribute__((ext_vector_type(4)));

constexpr int SCAN_CHUNK  = 1024;
constexpr int SCAN_BLOCKS = (NN + SCAN_CHUNK - 1) / SCAN_CHUNK; // 98
constexpr int NXCD        = 8;
constexpr int RSZ         = NN / NXCD;          // 12500 dst-range per XCD
constexpr int FILL_BPX    = 192;                // blocks per XCD-range
constexpr int FILL_GRID   = NXCD * FILL_BPX;    // 1536

// ---- bf16 helpers (storage bf16, arithmetic fp32) ----
__device__ inline float bflo(u32 u) { return __uint_as_float(u << 16); }
__device__ inline float bfhi(u32 u) { return __uint_as_float(u & 0xFFFF0000u); }
__device__ inline u16 f2bf(float f) {
    u32 u = __float_as_uint(f);
    u += 0x7FFFu + ((u >> 16) & 1u); // RNE
    return (u16)(u >> 16);
}
__device__ inline u32 pack2(float a, float b) {
    return (u32)f2bf(a) | ((u32)f2bf(b) << 16);
}

// ---------------- CSR build (XCD-range-partitioned scatter) ----------------
// range r = dst / RSZ; block handles range blockIdx.x % 8 so (with round-robin
// blockIdx->XCD dispatch) each cnt/col line is written by ONE XCD's L2 only.
// Correctness does not depend on the mapping (ranges partition the edges).

__global__ __launch_bounds__(256) void k_count(const int* __restrict__ dst,
                                               int* __restrict__ cnt) {
    const int range = blockIdx.x & (NXCD - 1);
    const int lo = range * RSZ, hi = lo + RSZ;
    for (int c = (blockIdx.x >> 3) * 256 + threadIdx.x; c < NE / 4;
         c += (FILL_GRID / NXCD) * 256) {
        const int4 d4 = reinterpret_cast<const int4*>(dst)[c];
        if (d4.x >= lo && d4.x < hi) atomicAdd(&cnt[d4.x], 1);
        if (d4.y >= lo && d4.y < hi) atomicAdd(&cnt[d4.y], 1);
        if (d4.z >= lo && d4.z < hi) atomicAdd(&cnt[d4.z], 1);
        if (d4.w >= lo && d4.w < hi) atomicAdd(&cnt[d4.w], 1);
    }
}

__global__ void k_scan1(const int* __restrict__ cnt, int* __restrict__ rp,
                        int* __restrict__ tot) {
    __shared__ int lds[256];
    const int t    = threadIdx.x;
    const int base = blockIdx.x * SCAN_CHUNK + t * 4;
    int v[4];
#pragma unroll
    for (int i = 0; i < 4; ++i) v[i] = (base + i < NN) ? cnt[base + i] : 0;
    const int s = v[0] + v[1] + v[2] + v[3];
    lds[t] = s;
    __syncthreads();
    int val = s;
    for (int off = 1; off < 256; off <<= 1) {
        int other = (t >= off) ? lds[t - off] : 0;
        __syncthreads();
        val += other;
        lds[t] = val;
        __syncthreads();
    }
    int e = val - s; // exclusive prefix within block
#pragma unroll
    for (int i = 0; i < 4; ++i) {
        if (base + i < NN) rp[base + i] = e;
        e += v[i];
    }
    if (t == 255) tot[blockIdx.x] = val;
}

__global__ void k_scan2(int* __restrict__ tot, int* __restrict__ rp) {
    if (threadIdx.x == 0 && blockIdx.x == 0) {
        int run = 0;
        for (int b = 0; b < SCAN_BLOCKS; ++b) { int v = tot[b]; tot[b] = run; run += v; }
        rp[NN] = run; // == NE
    }
}

// add block offsets; init fill cursor cur[d] = rp[d]
__global__ void k_scan3(int* __restrict__ rp, const int* __restrict__ tot,
                        int* __restrict__ cur) {
    int idx = blockIdx.x * 256 + threadIdx.x;
    if (idx < NN) {
        const int v = rp[idx] + tot[idx >> 10];
        rp[idx]  = v;
        cur[idx] = v;
    }
}

__global__ __launch_bounds__(256) void k_fill(const int* __restrict__ src,
                                              const int* __restrict__ dst,
                                              int* __restrict__ cur,
                                              int* __restrict__ col) {
    const int range = blockIdx.x & (NXCD - 1);
    const int lo = range * RSZ, hi = lo + RSZ;
    for (int c = (blockIdx.x >> 3) * 256 + threadIdx.x; c < NE / 4;
         c += (FILL_GRID / NXCD) * 256) {
        const int4 d4 = reinterpret_cast<const int4*>(dst)[c];
        const int4 s4 = reinterpret_cast<const int4*>(src)[c];
        if (d4.x >= lo && d4.x < hi) col[atomicAdd(&cur[d4.x], 1)] = s4.x;
        if (d4.y >= lo && d4.y < hi) col[atomicAdd(&cur[d4.y], 1)] = s4.y;
        if (d4.z >= lo && d4.z < hi) col[atomicAdd(&cur[d4.z], 1)] = s4.z;
        if (d4.w >= lo && d4.w < hi) col[atomicAdd(&cur[d4.w], 1)] = s4.w;
    }
}

// ---------------- weight prep: WT[n][k] = bf16(W[k][n]), 7 matrices ----------------

struct WTArgs { const float* w[7]; u16* o[7]; };

__global__ void k_wt(WTArgs a) {
    const int m = blockIdx.y;   // which matrix
    const int n = blockIdx.x;   // output row = W column
    const int k = threadIdx.x;  // 128
    a.o[m][n * HD + k] = f2bf(a.w[m][k * HD + n]);
}

// ---------------- mean aggregation: one node per wave, 4-group edge striping ----------------

__device__ inline void acc8(float* a, uint4 v) {
    a[0] += bflo(v.x); a[1] += bfhi(v.x);
    a[2] += bflo(v.y); a[3] += bfhi(v.y);
    a[4] += bflo(v.z); a[5] += bfhi(v.z);
    a[6] += bflo(v.w); a[7] += bfhi(v.w);
}

__global__ __launch_bounds__(256) void k_agg(const u16* __restrict__ h,
                                             const int* __restrict__ rp,
                                             const int* __restrict__ col,
                                             u16* __restrict__ mean) {
    const int lane = threadIdx.x & 63;
    const int node = blockIdx.x * 4 + (threadIdx.x >> 6); // NN % 4 == 0
    const int grp  = lane >> 4;   // 0..3: edge stripe
    const int li   = lane & 15;   // 16B chunk within row
    const int r0 = rp[node], r1 = rp[node + 1];
    const size_t lof = (size_t)li * 8;
    float a[8];
#pragma unroll
    for (int i = 0; i < 8; ++i) a[i] = 0.f;
    int e = r0 + grp;
    for (; e + 4 < r1; e += 8) { // 2x unroll over this group's stripe
        const int s0 = col[e], s1 = col[e + 4];
        const uint4 v0 = *reinterpret_cast<const uint4*>(&h[(size_t)s0 * HD + lof]);
        const uint4 v1 = *reinterpret_cast<const uint4*>(&h[(size_t)s1 * HD + lof]);
        acc8(a, v0); acc8(a, v1);
    }
    if (e < r1) {
        const uint4 v = *reinterpret_cast<const uint4*>(&h[(size_t)col[e] * HD + lof]);
        acc8(a, v);
    }
    // combine the 4 groups (lanes l, l+16, l+32, l+48)
#pragma unroll
    for (int i = 0; i < 8; ++i) {
        a[i] += __shfl_xor(a[i], 16);
        a[i] += __shfl_xor(a[i], 32);
    }
    if (lane < 16) {
        const float inv = 1.0f / fmaxf((float)(r1 - r0), 1.0f);
        uint4 o;
        o.x = pack2(a[0] * inv, a[1] * inv);
        o.y = pack2(a[2] * inv, a[3] * inv);
        o.z = pack2(a[4] * inv, a[5] * inv);
        o.w = pack2(a[6] * inv, a[7] * inv);
        *reinterpret_cast<uint4*>(&mean[(size_t)node * HD + lof]) = o;
    }
}

// ---------------- MFMA GEMM: out = A1@W1 (+ A2@W2) + bias ----------------
// 256 threads = 4 waves; block tile 64x128; wave tile 16x128.
// STATS: accumulate column sum/sumsq of outputs into stats[256] via
// wave shuffle -> LDS -> 256 global atomicAdds per block.

template <int A1F32, int RELU, int STATS>
__global__ __launch_bounds__(256) void k_mgemm(
    const void* __restrict__ A1p, const u16* __restrict__ W1T,
    const u16* __restrict__ A2, const u16* __restrict__ W2T,
    const float* __restrict__ bias, u16* __restrict__ out,
    float* __restrict__ stats)
{
    const int t    = threadIdx.x;
    const int wv   = t >> 6;
    const int lane = t & 63;
    const int lid  = lane & 15;   // A-row / B-col / D-col within tile
    const int kseg = lane >> 4;   // 0..3
    const int row0 = blockIdx.x * 64 + wv * 16;
    const int r    = row0 + lid;
    const bool rok = r < NN;

    f32x4 acc[8];
#pragma unroll
    for (int c = 0; c < 8; ++c) acc[c] = (f32x4){0.f, 0.f, 0.f, 0.f};

    for (int pass = 0; pass < 2; ++pass) {
        if (pass == 1 && A2 == nullptr) break;
        const u16* WT = pass ? W2T : W1T;
#pragma unroll
        for (int kk = 0; kk < 4; ++kk) {
            const int kof = kk * 32 + kseg * 8;
            bf16x8 af;
            if (A1F32 && pass == 0) {
                const float* A = (const float*)A1p;
                if (rok) {
                    const float4 f0 = *reinterpret_cast<const float4*>(&A[(size_t)r * HD + kof]);
                    const float4 f1 = *reinterpret_cast<const float4*>(&A[(size_t)r * HD + kof + 4]);
                    af[0] = (short)f2bf(f0.x); af[1] = (short)f2bf(f0.y);
                    af[2] = (short)f2bf(f0.z); af[3] = (short)f2bf(f0.w);
                    af[4] = (short)f2bf(f1.x); af[5] = (short)f2bf(f1.y);
                    af[6] = (short)f2bf(f1.z); af[7] = (short)f2bf(f1.w);
                } else {
                    af = (bf16x8)0;
                }
            } else {
                const u16* A = pass ? A2 : (const u16*)A1p;
                af = rok ? *reinterpret_cast<const bf16x8*>(&A[(size_t)r * HD + kof])
                         : (bf16x8)0;
            }
#pragma unroll
            for (int c = 0; c < 8; ++c) {
                const bf16x8 bf =
                    *reinterpret_cast<const bf16x8*>(&WT[(size_t)(c * 16 + lid) * HD + kof]);
                acc[c] = __builtin_amdgcn_mfma_f32_16x16x32_bf16(af, bf, acc[c], 0, 0, 0);
            }
        }
    }

    float sv[8], qv[8];
#pragma unroll
    for (int c = 0; c < 8; ++c) {
        const int colc = c * 16 + lid;
        const float bv = bias[colc];
        float s = 0.f, q = 0.f;
#pragma unroll
        for (int j = 0; j < 4; ++j) {
            const int rr = row0 + kseg * 4 + j;
            if (rr < NN) {
                float o = acc[c][j] + bv;
                if (RELU) o = fmaxf(o, 0.f);
                out[(size_t)rr * HD + colc] = f2bf(o);
                s += o;
                q += o * o;
            }
        }
        sv[c] = s; qv[c] = q;
    }

    if constexpr (STATS) {
        __shared__ float ls[4][HD], lq[4][HD];
#pragma unroll
        for (int c = 0; c < 8; ++c) {
            sv[c] += __shfl_xor(sv[c], 16);
            sv[c] += __shfl_xor(sv[c], 32);
            qv[c] += __shfl_xor(qv[c], 16);
            qv[c] += __shfl_xor(qv[c], 32);
        }
        if (lane < 16) {
#pragma unroll
            for (int c = 0; c < 8; ++c) {
                ls[wv][c * 16 + lid] = sv[c];
                lq[wv][c * 16 + lid] = qv[c];
            }
        }
        __syncthreads();
        if (t < HD) {
            const float s = (ls[0][t] + ls[1][t]) + (ls[2][t] + ls[3][t]);
            atomicAdd(&stats[t], s);
        } else {
            const int j = t - HD;
            const float q = (lq[0][j] + lq[1][j]) + (lq[2][j] + lq[3][j]);
            atomicAdd(&stats[HD + j], q);
        }
    }
}

// ---------------- fused BN-finalize + relu + residual (+ classifier) ----------------
// thread covers 4 cols of one row; 32 threads per row.

template <int CLS>
__global__ __launch_bounds__(256) void k_apply(
    const u16* __restrict__ outb, const float* __restrict__ stats,
    const float* __restrict__ g, const float* __restrict__ bt,
    u16* __restrict__ hb, const float* __restrict__ cw,
    const float* __restrict__ cb, float* __restrict__ logits)
{
    const int t = threadIdx.x;
    const size_t idx4 = (size_t)blockIdx.x * 256 + t;
    const int j = (int)(idx4 & 31) * 4; // column base
    const float4 svv = *reinterpret_cast<const float4*>(&stats[j]);
    const float4 qvv = *reinterpret_cast<const float4*>(&stats[HD + j]);
    const float4 gv  = *reinterpret_cast<const float4*>(&g[j]);
    const float4 bv  = *reinterpret_cast<const float4*>(&bt[j]);
    const float invn = 1.0f / (float)NN;
    float sc[4], sh[4];
    {
        const float sa[4] = {svv.x, svv.y, svv.z, svv.w};
        const float qa[4] = {qvv.x, qvv.y, qvv.z, qvv.w};
        const float ga[4] = {gv.x, gv.y, gv.z, gv.w};
        const float ba[4] = {bv.x, bv.y, bv.z, bv.w};
#pragma unroll
        for (int i = 0; i < 4; ++i) {
            const float mean = sa[i] * invn;
            const float var  = qa[i] * invn - mean * mean;
            sc[i] = ga[i] * rsqrtf(var + EPSI);
            sh[i] = ba[i] - mean * sc[i];
        }
    }
    const uint2 o  = reinterpret_cast<const uint2*>(outb)[idx4];
    const uint2 hv = reinterpret_cast<const uint2*>(hb)[idx4];
    const float r0 = fmaxf(bflo(o.x) * sc[0] + sh[0], 0.f) + bflo(hv.x);
    const float r1 = fmaxf(bfhi(o.x) * sc[1] + sh[1], 0.f) + bfhi(hv.x);
    const float r2 = fmaxf(bflo(o.y) * sc[2] + sh[2], 0.f) + bflo(hv.y);
    const float r3 = fmaxf(bfhi(o.y) * sc[3] + sh[3], 0.f) + bfhi(hv.y);
    reinterpret_cast<uint2*>(hb)[idx4] = make_uint2(pack2(r0, r1), pack2(r2, r3));

    if constexpr (CLS) {
        const float4 w01 = *reinterpret_cast<const float4*>(&cw[j * 2]);
        const float4 w23 = *reinterpret_cast<const float4*>(&cw[j * 2 + 4]);
        float p0 = r0 * w01.x + r1 * w01.z + r2 * w23.x + r3 * w23.z;
        float p1 = r0 * w01.y + r1 * w01.w + r2 * w23.y + r3 * w23.w;
#pragma unroll
        for (int off = 1; off <= 16; off <<= 1) {
            p0 += __shfl_xor(p0, off);
            p1 += __shfl_xor(p1, off);
        }
        if ((t & 31) == 0) {
            const size_t row = idx4 >> 5;
            logits[row * 2 + 0] = p0 + cb[0];
            logits[row * 2 + 1] = p1 + cb[1];
        }
    }
}

// ---------------- launch ----------------

extern "C" void kernel_launch(void* const* d_in, const int* in_sizes, int n_in,
                              void* d_out, int out_size, void* d_ws, size_t ws_size,
                              hipStream_t stream) {
    const float* x     = (const float*)d_in[0];
    const int*   ei    = (const int*)d_in[1];
    const float* in_w  = (const float*)d_in[2];
    const float* in_b  = (const float*)d_in[3];
    const float* cls_w = (const float*)d_in[4];
    const float* cls_b = (const float*)d_in[5];
    const float* blk_w[3][5]; // lw, lb, rw, g, bt
    for (int bidx = 0; bidx < 3; ++bidx)
        for (int k = 0; k < 5; ++k)
            blk_w[bidx][k] = (const float*)d_in[6 + bidx * 5 + k];

    const int* src = ei;
    const int* dst = ei + NE;

    // workspace layout (~59 MB; big buffers bf16)
    size_t off = 0;
    auto alloc = [&](size_t bytes) {
        void* p = (char*)d_ws + off;
        off += (bytes + 255) & ~(size_t)255;
        return p;
    };
    u16*   h     = (u16*)alloc((size_t)NN * HD * 2);   // 25.6 MB
    u16*   tmp   = (u16*)alloc((size_t)NN * HD * 2);   // 25.6 MB (mean, then pre-BN out)
    int*   rp    = (int*)alloc((size_t)(NN + 1) * 4);
    int*   cnt   = (int*)alloc((size_t)NN * 4);        // counts, then fill cursor
    float* stats = (float*)alloc((size_t)3 * 256 * 4); // adjacent to cnt: one memset
    int*   col   = (int*)alloc((size_t)NE * 4);        // 6.4 MB
    int*   stot  = (int*)alloc((size_t)SCAN_BLOCKS * 4);
    u16*   wtb   = (u16*)alloc((size_t)7 * HD * HD * 2); // 224 KB transposed bf16 weights
    (void)ws_size; (void)n_in; (void)in_sizes; (void)out_size;

    // zero cnt + the 3 stats buffers in one memset (allocated adjacently)
    const size_t cnt_pad = ((size_t)NN * 4 + 255) & ~(size_t)255;
    hipMemsetAsync(cnt, 0, cnt_pad + 3 * 256 * 4, stream);

    // transposed bf16 weights: [0]=in_w, then per block lw, rw
    WTArgs wa;
    wa.w[0] = in_w;
    for (int bidx = 0; bidx < 3; ++bidx) {
        wa.w[1 + bidx * 2] = blk_w[bidx][0]; // lw
        wa.w[2 + bidx * 2] = blk_w[bidx][2]; // rw
    }
    for (int m = 0; m < 7; ++m) wa.o[m] = wtb + (size_t)m * HD * HD;
    k_wt<<<dim3(HD, 7), HD, 0, stream>>>(wa);

    // CSR build (XCD-range-partitioned)
    k_count<<<FILL_GRID, 256, 0, stream>>>(dst, cnt);
    k_scan1<<<SCAN_BLOCKS, 256, 0, stream>>>(cnt, rp, stot);
    k_scan2<<<1, 1, 0, stream>>>(stot, rp);
    k_scan3<<<(NN + 255) / 256, 256, 0, stream>>>(rp, stot, cnt);
    k_fill<<<FILL_GRID, 256, 0, stream>>>(src, dst, cnt, col);

    const int gemm_grid  = (NN + 63) / 64;
    const int apply_grid = NN * 32 / 256; // 12500, exact

    // input layer: h = relu(x @ in_w + in_b)
    k_mgemm<1, 1, 0><<<gemm_grid, 256, 0, stream>>>(x, wtb, nullptr, nullptr, in_b, h, nullptr);

    for (int bidx = 0; bidx < 3; ++bidx) {
        const u16* lwT = wtb + (size_t)(1 + bidx * 2) * HD * HD;
        const u16* rwT = wtb + (size_t)(2 + bidx * 2) * HD * HD;
        const float* lb = blk_w[bidx][1];
        const float* g  = blk_w[bidx][3];
        const float* bt = blk_w[bidx][4];
        float* st = stats + bidx * 256;
        k_agg<<<NN / 4, 256, 0, stream>>>(h, rp, col, tmp);
        k_mgemm<0, 0, 1><<<gemm_grid, 256, 0, stream>>>(tmp, lwT, h, rwT, lb, tmp, st);
        if (bidx < 2)
            k_apply<0><<<apply_grid, 256, 0, stream>>>(tmp, st, g, bt, h,
                                                       nullptr, nullptr, nullptr);
        else
            k_apply<1><<<apply_grid, 256, 0, stream>>>(tmp, st, g, bt, h,
                                                       cls_w, cls_b, (float*)d_out);
    }
}

// Round 6
// 558.567 us; speedup vs baseline: 2.2343x; 1.2456x over previous
//
#include <hip/hip_runtime.h>

#define NN 100000
#define NE 1600000
#define HD 128
#define EPSI 1e-5f

using u32 = unsigned int;
using u16 = unsigned short;

typedef short bf16x8 __attribute__((ext_vector_type(8)));
typedef float f32x4  __attribute__((ext_vector_type(4)));

constexpr int SCAN_CHUNK  = 1024;
constexpr int SCAN_BLOCKS = (NN + SCAN_CHUNK - 1) / SCAN_CHUNK; // 98
constexpr int NXCD        = 8;
constexpr int RSZ         = NN / NXCD;          // 12500 dst-range per XCD
constexpr int FILL_BPX    = 192;                // blocks per XCD-range
constexpr int FILL_GRID   = NXCD * FILL_BPX;    // 1536

// ---- bf16 helpers (storage bf16, arithmetic fp32) ----
__device__ inline float bflo(u32 u) { return __uint_as_float(u << 16); }
__device__ inline float bfhi(u32 u) { return __uint_as_float(u & 0xFFFF0000u); }
__device__ inline u16 f2bf(float f) {
    u32 u = __float_as_uint(f);
    u += 0x7FFFu + ((u >> 16) & 1u); // RNE
    return (u16)(u >> 16);
}
__device__ inline u32 pack2(float a, float b) {
    return (u32)f2bf(a) | ((u32)f2bf(b) << 16);
}

// ---------------- CSR build (XCD-range-partitioned scatter) ----------------

__global__ __launch_bounds__(256) void k_count(const int* __restrict__ dst,
                                               int* __restrict__ cnt) {
    const int range = blockIdx.x & (NXCD - 1);
    const int lo = range * RSZ, hi = lo + RSZ;
    for (int c = (blockIdx.x >> 3) * 256 + threadIdx.x; c < NE / 4;
         c += (FILL_GRID / NXCD) * 256) {
        const int4 d4 = reinterpret_cast<const int4*>(dst)[c];
        if (d4.x >= lo && d4.x < hi) atomicAdd(&cnt[d4.x], 1);
        if (d4.y >= lo && d4.y < hi) atomicAdd(&cnt[d4.y], 1);
        if (d4.z >= lo && d4.z < hi) atomicAdd(&cnt[d4.z], 1);
        if (d4.w >= lo && d4.w < hi) atomicAdd(&cnt[d4.w], 1);
    }
}

__global__ void k_scan1(const int* __restrict__ cnt, int* __restrict__ rp,
                        int* __restrict__ tot) {
    __shared__ int lds[256];
    const int t    = threadIdx.x;
    const int base = blockIdx.x * SCAN_CHUNK + t * 4;
    int v[4];
#pragma unroll
    for (int i = 0; i < 4; ++i) v[i] = (base + i < NN) ? cnt[base + i] : 0;
    const int s = v[0] + v[1] + v[2] + v[3];
    lds[t] = s;
    __syncthreads();
    int val = s;
    for (int off = 1; off < 256; off <<= 1) {
        int other = (t >= off) ? lds[t - off] : 0;
        __syncthreads();
        val += other;
        lds[t] = val;
        __syncthreads();
    }
    int e = val - s; // exclusive prefix within block
#pragma unroll
    for (int i = 0; i < 4; ++i) {
        if (base + i < NN) rp[base + i] = e;
        e += v[i];
    }
    if (t == 255) tot[blockIdx.x] = val;
}

__global__ void k_scan2(int* __restrict__ tot, int* __restrict__ rp) {
    if (threadIdx.x == 0 && blockIdx.x == 0) {
        int run = 0;
        for (int b = 0; b < SCAN_BLOCKS; ++b) { int v = tot[b]; tot[b] = run; run += v; }
        rp[NN] = run; // == NE
    }
}

// add block offsets; init fill cursor cur[d] = rp[d]
__global__ void k_scan3(int* __restrict__ rp, const int* __restrict__ tot,
                        int* __restrict__ cur) {
    int idx = blockIdx.x * 256 + threadIdx.x;
    if (idx < NN) {
        const int v = rp[idx] + tot[idx >> 10];
        rp[idx]  = v;
        cur[idx] = v;
    }
}

__global__ __launch_bounds__(256) void k_fill(const int* __restrict__ src,
                                              const int* __restrict__ dst,
                                              int* __restrict__ cur,
                                              int* __restrict__ col) {
    const int range = blockIdx.x & (NXCD - 1);
    const int lo = range * RSZ, hi = lo + RSZ;
    for (int c = (blockIdx.x >> 3) * 256 + threadIdx.x; c < NE / 4;
         c += (FILL_GRID / NXCD) * 256) {
        const int4 d4 = reinterpret_cast<const int4*>(dst)[c];
        const int4 s4 = reinterpret_cast<const int4*>(src)[c];
        if (d4.x >= lo && d4.x < hi) col[atomicAdd(&cur[d4.x], 1)] = s4.x;
        if (d4.y >= lo && d4.y < hi) col[atomicAdd(&cur[d4.y], 1)] = s4.y;
        if (d4.z >= lo && d4.z < hi) col[atomicAdd(&cur[d4.z], 1)] = s4.z;
        if (d4.w >= lo && d4.w < hi) col[atomicAdd(&cur[d4.w], 1)] = s4.w;
    }
}

// ---------------- weight prep: WT[n][k] = bf16(W[k][n]), 7 matrices ----------------

struct WTArgs { const float* w[7]; u16* o[7]; };

__global__ void k_wt(WTArgs a) {
    const int m = blockIdx.y;   // which matrix
    const int n = blockIdx.x;   // output row = W column
    const int k = threadIdx.x;  // 128
    a.o[m][n * HD + k] = f2bf(a.w[m][k * HD + n]);
}

// ---------------- mean aggregation: one node per wave, 4-group edge striping ----------------

__device__ inline void acc8(float* a, uint4 v) {
    a[0] += bflo(v.x); a[1] += bfhi(v.x);
    a[2] += bflo(v.y); a[3] += bfhi(v.y);
    a[4] += bflo(v.z); a[5] += bfhi(v.z);
    a[6] += bflo(v.w); a[7] += bfhi(v.w);
}

__global__ __launch_bounds__(256) void k_agg(const u16* __restrict__ h,
                                             const int* __restrict__ rp,
                                             const int* __restrict__ col,
                                             u16* __restrict__ mean) {
    const int lane = threadIdx.x & 63;
    const int node = blockIdx.x * 4 + (threadIdx.x >> 6); // NN % 4 == 0
    const int grp  = lane >> 4;   // 0..3: edge stripe
    const int li   = lane & 15;   // 16B chunk within row
    const int r0 = rp[node], r1 = rp[node + 1];
    const size_t lof = (size_t)li * 8;
    float a[8];
#pragma unroll
    for (int i = 0; i < 8; ++i) a[i] = 0.f;
    int e = r0 + grp;
    for (; e + 4 < r1; e += 8) { // 2x unroll over this group's stripe
        const int s0 = col[e], s1 = col[e + 4];
        const uint4 v0 = *reinterpret_cast<const uint4*>(&h[(size_t)s0 * HD + lof]);
        const uint4 v1 = *reinterpret_cast<const uint4*>(&h[(size_t)s1 * HD + lof]);
        acc8(a, v0); acc8(a, v1);
    }
    if (e < r1) {
        const uint4 v = *reinterpret_cast<const uint4*>(&h[(size_t)col[e] * HD + lof]);
        acc8(a, v);
    }
    // combine the 4 groups (lanes l, l+16, l+32, l+48)
#pragma unroll
    for (int i = 0; i < 8; ++i) {
        a[i] += __shfl_xor(a[i], 16);
        a[i] += __shfl_xor(a[i], 32);
    }
    if (lane < 16) {
        const float inv = 1.0f / fmaxf((float)(r1 - r0), 1.0f);
        uint4 o;
        o.x = pack2(a[0] * inv, a[1] * inv);
        o.y = pack2(a[2] * inv, a[3] * inv);
        o.z = pack2(a[4] * inv, a[5] * inv);
        o.w = pack2(a[6] * inv, a[7] * inv);
        *reinterpret_cast<uint4*>(&mean[(size_t)node * HD + lof]) = o;
    }
}

// ---------------- MFMA GEMM: out = A1@W1 (+ A2@W2) + bias ----------------
// 256 threads = 4 waves; block tile 256x128; wave tile 64x128 (4 row-frags).
// One B-fragment load feeds 4 independent MFMAs -> load latency hidden by ILP.
// STATS: column sum/sumsq via wave shuffle -> LDS -> 256 atomicAdds per block.

template <int A1F32, int RELU, int STATS>
__global__ __launch_bounds__(256) void k_mgemm(
    const void* __restrict__ A1p, const u16* __restrict__ W1T,
    const u16* __restrict__ A2, const u16* __restrict__ W2T,
    const float* __restrict__ bias, u16* __restrict__ out,
    float* __restrict__ stats)
{
    const int t    = threadIdx.x;
    const int wv   = t >> 6;
    const int lane = t & 63;
    const int lid  = lane & 15;   // A-row / B-col / D-col within tile
    const int kseg = lane >> 4;   // 0..3
    const int row0 = blockIdx.x * 256 + wv * 64;   // wave's 64-row tile

    f32x4 acc[4][8];
#pragma unroll
    for (int rf = 0; rf < 4; ++rf)
#pragma unroll
        for (int c = 0; c < 8; ++c) acc[rf][c] = (f32x4){0.f, 0.f, 0.f, 0.f};

    int  ar[4];
    bool rok[4];
#pragma unroll
    for (int rf = 0; rf < 4; ++rf) {
        ar[rf]  = row0 + rf * 16 + lid;
        rok[rf] = ar[rf] < NN;
    }

    for (int pass = 0; pass < 2; ++pass) {
        if (pass == 1 && A2 == nullptr) break;
        const u16* WT = pass ? W2T : W1T;
#pragma unroll
        for (int kk = 0; kk < 4; ++kk) {
            const int kof = kk * 32 + kseg * 8;
            bf16x8 af[4];
#pragma unroll
            for (int rf = 0; rf < 4; ++rf) {
                if (A1F32 && pass == 0) {
                    const float* A = (const float*)A1p;
                    if (rok[rf]) {
                        const float4 f0 = *reinterpret_cast<const float4*>(&A[(size_t)ar[rf] * HD + kof]);
                        const float4 f1 = *reinterpret_cast<const float4*>(&A[(size_t)ar[rf] * HD + kof + 4]);
                        af[rf][0] = (short)f2bf(f0.x); af[rf][1] = (short)f2bf(f0.y);
                        af[rf][2] = (short)f2bf(f0.z); af[rf][3] = (short)f2bf(f0.w);
                        af[rf][4] = (short)f2bf(f1.x); af[rf][5] = (short)f2bf(f1.y);
                        af[rf][6] = (short)f2bf(f1.z); af[rf][7] = (short)f2bf(f1.w);
                    } else {
                        af[rf] = (bf16x8)0;
                    }
                } else {
                    const u16* A = pass ? A2 : (const u16*)A1p;
                    af[rf] = rok[rf]
                        ? *reinterpret_cast<const bf16x8*>(&A[(size_t)ar[rf] * HD + kof])
                        : (bf16x8)0;
                }
            }
#pragma unroll
            for (int c = 0; c < 8; ++c) {
                const bf16x8 bf =
                    *reinterpret_cast<const bf16x8*>(&WT[(size_t)(c * 16 + lid) * HD + kof]);
#pragma unroll
                for (int rf = 0; rf < 4; ++rf)
                    acc[rf][c] = __builtin_amdgcn_mfma_f32_16x16x32_bf16(af[rf], bf, acc[rf][c], 0, 0, 0);
            }
        }
    }

    float bv[8];
#pragma unroll
    for (int c = 0; c < 8; ++c) bv[c] = bias[c * 16 + lid];

    float sv[8], qv[8];
#pragma unroll
    for (int c = 0; c < 8; ++c) { sv[c] = 0.f; qv[c] = 0.f; }

#pragma unroll
    for (int rf = 0; rf < 4; ++rf) {
#pragma unroll
        for (int c = 0; c < 8; ++c) {
            const int colc = c * 16 + lid;
#pragma unroll
            for (int j = 0; j < 4; ++j) {
                const int rrow = row0 + rf * 16 + kseg * 4 + j;
                if (rrow < NN) {
                    float o = acc[rf][c][j] + bv[c];
                    if (RELU) o = fmaxf(o, 0.f);
                    out[(size_t)rrow * HD + colc] = f2bf(o);
                    sv[c] += o;
                    qv[c] += o * o;
                }
            }
        }
    }

    if constexpr (STATS) {
        __shared__ float ls[4][HD], lq[4][HD];
#pragma unroll
        for (int c = 0; c < 8; ++c) {
            sv[c] += __shfl_xor(sv[c], 16);
            sv[c] += __shfl_xor(sv[c], 32);
            qv[c] += __shfl_xor(qv[c], 16);
            qv[c] += __shfl_xor(qv[c], 32);
        }
        if (lane < 16) {
#pragma unroll
            for (int c = 0; c < 8; ++c) {
                ls[wv][c * 16 + lid] = sv[c];
                lq[wv][c * 16 + lid] = qv[c];
            }
        }
        __syncthreads();
        if (t < HD) {
            const float s = (ls[0][t] + ls[1][t]) + (ls[2][t] + ls[3][t]);
            atomicAdd(&stats[t], s);
        } else {
            const int j = t - HD;
            const float q = (lq[0][j] + lq[1][j]) + (lq[2][j] + lq[3][j]);
            atomicAdd(&stats[HD + j], q);
        }
    }
}

// ---------------- fused BN-finalize + relu + residual (+ classifier) ----------------
// thread covers 4 cols of one row; 32 threads per row.

template <int CLS>
__global__ __launch_bounds__(256) void k_apply(
    const u16* __restrict__ outb, const float* __restrict__ stats,
    const float* __restrict__ g, const float* __restrict__ bt,
    u16* __restrict__ hb, const float* __restrict__ cw,
    const float* __restrict__ cb, float* __restrict__ logits)
{
    const int t = threadIdx.x;
    const size_t idx4 = (size_t)blockIdx.x * 256 + t;
    const int j = (int)(idx4 & 31) * 4; // column base
    const float4 svv = *reinterpret_cast<const float4*>(&stats[j]);
    const float4 qvv = *reinterpret_cast<const float4*>(&stats[HD + j]);
    const float4 gv  = *reinterpret_cast<const float4*>(&g[j]);
    const float4 bv  = *reinterpret_cast<const float4*>(&bt[j]);
    const float invn = 1.0f / (float)NN;
    float sc[4], sh[4];
    {
        const float sa[4] = {svv.x, svv.y, svv.z, svv.w};
        const float qa[4] = {qvv.x, qvv.y, qvv.z, qvv.w};
        const float ga[4] = {gv.x, gv.y, gv.z, gv.w};
        const float ba[4] = {bv.x, bv.y, bv.z, bv.w};
#pragma unroll
        for (int i = 0; i < 4; ++i) {
            const float mean = sa[i] * invn;
            const float var  = qa[i] * invn - mean * mean;
            sc[i] = ga[i] * rsqrtf(var + EPSI);
            sh[i] = ba[i] - mean * sc[i];
        }
    }
    const uint2 o  = reinterpret_cast<const uint2*>(outb)[idx4];
    const uint2 hv = reinterpret_cast<const uint2*>(hb)[idx4];
    const float r0 = fmaxf(bflo(o.x) * sc[0] + sh[0], 0.f) + bflo(hv.x);
    const float r1 = fmaxf(bfhi(o.x) * sc[1] + sh[1], 0.f) + bfhi(hv.x);
    const float r2 = fmaxf(bflo(o.y) * sc[2] + sh[2], 0.f) + bflo(hv.y);
    const float r3 = fmaxf(bfhi(o.y) * sc[3] + sh[3], 0.f) + bfhi(hv.y);
    reinterpret_cast<uint2*>(hb)[idx4] = make_uint2(pack2(r0, r1), pack2(r2, r3));

    if constexpr (CLS) {
        const float4 w01 = *reinterpret_cast<const float4*>(&cw[j * 2]);
        const float4 w23 = *reinterpret_cast<const float4*>(&cw[j * 2 + 4]);
        float p0 = r0 * w01.x + r1 * w01.z + r2 * w23.x + r3 * w23.z;
        float p1 = r0 * w01.y + r1 * w01.w + r2 * w23.y + r3 * w23.w;
#pragma unroll
        for (int off = 1; off <= 16; off <<= 1) {
            p0 += __shfl_xor(p0, off);
            p1 += __shfl_xor(p1, off);
        }
        if ((t & 31) == 0) {
            const size_t row = idx4 >> 5;
            logits[row * 2 + 0] = p0 + cb[0];
            logits[row * 2 + 1] = p1 + cb[1];
        }
    }
}

// ---------------- launch ----------------

extern "C" void kernel_launch(void* const* d_in, const int* in_sizes, int n_in,
                              void* d_out, int out_size, void* d_ws, size_t ws_size,
                              hipStream_t stream) {
    const float* x     = (const float*)d_in[0];
    const int*   ei    = (const int*)d_in[1];
    const float* in_w  = (const float*)d_in[2];
    const float* in_b  = (const float*)d_in[3];
    const float* cls_w = (const float*)d_in[4];
    const float* cls_b = (const float*)d_in[5];
    const float* blk_w[3][5]; // lw, lb, rw, g, bt
    for (int bidx = 0; bidx < 3; ++bidx)
        for (int k = 0; k < 5; ++k)
            blk_w[bidx][k] = (const float*)d_in[6 + bidx * 5 + k];

    const int* src = ei;
    const int* dst = ei + NE;

    // workspace layout (~59 MB; big buffers bf16)
    size_t off = 0;
    auto alloc = [&](size_t bytes) {
        void* p = (char*)d_ws + off;
        off += (bytes + 255) & ~(size_t)255;
        return p;
    };
    u16*   h     = (u16*)alloc((size_t)NN * HD * 2);   // 25.6 MB
    u16*   tmp   = (u16*)alloc((size_t)NN * HD * 2);   // 25.6 MB (mean, then pre-BN out)
    int*   rp    = (int*)alloc((size_t)(NN + 1) * 4);
    int*   cnt   = (int*)alloc((size_t)NN * 4);        // counts, then fill cursor
    float* stats = (float*)alloc((size_t)3 * 256 * 4); // adjacent to cnt: one memset
    int*   col   = (int*)alloc((size_t)NE * 4);        // 6.4 MB
    int*   stot  = (int*)alloc((size_t)SCAN_BLOCKS * 4);
    u16*   wtb   = (u16*)alloc((size_t)7 * HD * HD * 2); // 224 KB transposed bf16 weights
    (void)ws_size; (void)n_in; (void)in_sizes; (void)out_size;

    // zero cnt + the 3 stats buffers in one memset (allocated adjacently)
    const size_t cnt_pad = ((size_t)NN * 4 + 255) & ~(size_t)255;
    hipMemsetAsync(cnt, 0, cnt_pad + 3 * 256 * 4, stream);

    // transposed bf16 weights: [0]=in_w, then per block lw, rw
    WTArgs wa;
    wa.w[0] = in_w;
    for (int bidx = 0; bidx < 3; ++bidx) {
        wa.w[1 + bidx * 2] = blk_w[bidx][0]; // lw
        wa.w[2 + bidx * 2] = blk_w[bidx][2]; // rw
    }
    for (int m = 0; m < 7; ++m) wa.o[m] = wtb + (size_t)m * HD * HD;
    k_wt<<<dim3(HD, 7), HD, 0, stream>>>(wa);

    // CSR build (XCD-range-partitioned)
    k_count<<<FILL_GRID, 256, 0, stream>>>(dst, cnt);
    k_scan1<<<SCAN_BLOCKS, 256, 0, stream>>>(cnt, rp, stot);
    k_scan2<<<1, 1, 0, stream>>>(stot, rp);
    k_scan3<<<(NN + 255) / 256, 256, 0, stream>>>(rp, stot, cnt);
    k_fill<<<FILL_GRID, 256, 0, stream>>>(src, dst, cnt, col);

    const int gemm_grid  = (NN + 255) / 256; // 391 blocks, 256 rows each
    const int apply_grid = NN * 32 / 256;    // 12500, exact

    // input layer: h = relu(x @ in_w + in_b)
    k_mgemm<1, 1, 0><<<gemm_grid, 256, 0, stream>>>(x, wtb, nullptr, nullptr, in_b, h, nullptr);

    for (int bidx = 0; bidx < 3; ++bidx) {
        const u16* lwT = wtb + (size_t)(1 + bidx * 2) * HD * HD;
        const u16* rwT = wtb + (size_t)(2 + bidx * 2) * HD * HD;
        const float* lb = blk_w[bidx][1];
        const float* g  = blk_w[bidx][3];
        const float* bt = blk_w[bidx][4];
        float* st = stats + bidx * 256;
        k_agg<<<NN / 4, 256, 0, stream>>>(h, rp, col, tmp);
        k_mgemm<0, 0, 1><<<gemm_grid, 256, 0, stream>>>(tmp, lwT, h, rwT, lb, tmp, st);
        if (bidx < 2)
            k_apply<0><<<apply_grid, 256, 0, stream>>>(tmp, st, g, bt, h,
                                                       nullptr, nullptr, nullptr);
        else
            k_apply<1><<<apply_grid, 256, 0, stream>>>(tmp, st, g, bt, h,
                                                       cls_w, cls_b, (float*)d_out);
    }
}